// Round 2
// baseline (434.298 us; speedup 1.0000x reference)
//
#include <hip/hip_runtime.h>
#include <stdint.h>

#define N_ROWS 65536
#define N_CLS  1000
#define KPAD   1024
#define FEAT   256
#define MT     64          // rows per block
#define BK     64          // k per iteration
#define NIT    (KPAD/BK)   // 16

typedef _Float16 f16x8 __attribute__((ext_vector_type(8)));
typedef _Float16 f16x2 __attribute__((ext_vector_type(2)));
typedef float    f32x4 __attribute__((ext_vector_type(4)));

__device__ __forceinline__ f16x2 as_f16x2(uint32_t u) {
    union { uint32_t u; f16x2 h; } c; c.u = u; return c.h;
}

// Prep: centersT[n][c] = f16(centers[c][n]) zero-padded to KPAD;
// csqh[c] = f16(||centers[c]||^2) zero-padded; zero d_out.
__global__ __launch_bounds__(256) void prep_kernel(const float* __restrict__ centers,
                                                   ushort* __restrict__ centersT,
                                                   ushort* __restrict__ csqh,
                                                   float* __restrict__ out) {
    const int c = blockIdx.x;     // 0..1023
    const int n = threadIdx.x;    // 0..255
    float v = 0.f;
    if (c < N_CLS) v = centers[(size_t)c * FEAT + n];
    union { _Float16 h; ushort s; } cv; cv.h = (_Float16)v;
    centersT[(size_t)n * KPAD + c] = cv.s;
    float sq = v * v;
    #pragma unroll
    for (int off = 32; off > 0; off >>= 1) sq += __shfl_down(sq, off);
    __shared__ float red[4];
    if ((threadIdx.x & 63) == 0) red[threadIdx.x >> 6] = sq;
    __syncthreads();
    if (threadIdx.x == 0) {
        union { _Float16 h; ushort s; } cs;
        cs.h = (_Float16)(red[0] + red[1] + red[2] + red[3]);
        csqh[c] = cs.s;
        if (c == 0) out[0] = 0.f;
    }
}

// LDS layout: 16B chunks, XOR-swizzled: row r's logical k-chunk kl lives at
// physical chunk kl ^ (r&7). Conflict-free (2 dwords/bank per 16-lane phase)
// for both the staging writes and the b128 fragment reads. 40 KB total ->
// 4 blocks/CU; epilogue reductions alias the A buffer.
__global__ __launch_bounds__(256, 4) void main_kernel(const int* __restrict__ gt,
                                                      const float* __restrict__ features,
                                                      const ushort* __restrict__ centersT,
                                                      const ushort* __restrict__ csqh,
                                                      float* __restrict__ out) {
    __shared__ uint4 As4[MT * 8];    //  8 KB: A tile, 64 rows x 8 chunks
    __shared__ uint4 Bs4[FEAT * 8];  // 32 KB: B tile, 256 rows x 8 chunks

    const int tid  = threadIdx.x;
    const int m0   = blockIdx.x * MT;
    const int r    = tid >> 2;       // staging row 0..63
    const int kc2  = tid & 3;        // staging k-quarter (16 elems)
    const int lane = tid & 63;
    const int w    = tid >> 6;       // wave 0..3 -> cols w*64
    const int ml   = lane & 15;
    const int quad = lane >> 4;
    const int mls  = ml & 7;         // swizzle key for fragment reads

    f32x4 acc[4][4];
    #pragma unroll
    for (int i = 0; i < 4; i++)
        #pragma unroll
        for (int j = 0; j < 4; j++)
            #pragma unroll
            for (int k = 0; k < 4; k++) acc[i][j][k] = 0.f;

    uint32_t rcp = 0;    // packed rowcnt accumulator (lo16 + hi16)
    float    t2  = 0.f;  // scalar sum of mask*csq over this thread's elements
    const int*   gtrow = gt + (size_t)(m0 + r) * N_CLS;
    const uint4* ctv   = (const uint4*)centersT;   // chunk idx = n*128 + k/8

    for (int it = 0; it < NIT; ++it) {
        const int k0 = it * BK;
        const int kb = k0 + kc2 * 16;
        __syncthreads();

        // ---- load 16 gt ints (values are exactly {0,1}) ----
        int v[16];
        if (kb + 16 <= N_CLS) {
            const int4* p = (const int4*)(gtrow + kb);
            int4 a0 = p[0], a1 = p[1], a2 = p[2], a3 = p[3];
            v[0]=a0.x; v[1]=a0.y; v[2]=a0.z; v[3]=a0.w;
            v[4]=a1.x; v[5]=a1.y; v[6]=a1.z; v[7]=a1.w;
            v[8]=a2.x; v[9]=a2.y; v[10]=a2.z; v[11]=a2.w;
            v[12]=a3.x; v[13]=a3.y; v[14]=a3.z; v[15]=a3.w;
        } else {
            #pragma unroll
            for (int j = 0; j < 16; j++) {
                int k = kb + j;
                v[j] = (k < N_CLS) ? gtrow[k] : 0;
            }
        }
        // csqh pairs for this k-range (always in-bounds: padded to KPAD)
        uint4 cq0 = *(const uint4*)(csqh + kb);
        uint4 cq1 = *(const uint4*)(csqh + kb + 8);
        uint32_t cp[8] = {cq0.x, cq0.y, cq0.z, cq0.w, cq1.x, cq1.y, cq1.z, cq1.w};

        // ---- convert to packed f16 mask; fuse rowcnt + t2 ----
        uint32_t u[8];
        #pragma unroll
        for (int j = 0; j < 8; j++) {
            uint32_t t = (uint32_t)v[2*j] + ((uint32_t)v[2*j+1] << 16);
            rcp += t;                       // integer rowcnt, packed
            u[j] = t * 0x3C00u;             // {0,1} pair -> f16 {0.0,1.0} pair
            t2 = __builtin_amdgcn_fdot2(as_f16x2(u[j]), as_f16x2(cp[j]), t2, false);
        }

        // ---- A tile -> LDS (swizzled) ----
        {
            uint4* dst = &As4[r * 8];
            dst[(2*kc2)     ^ (r & 7)] = make_uint4(u[0], u[1], u[2], u[3]);
            dst[(2*kc2 + 1) ^ (r & 7)] = make_uint4(u[4], u[5], u[6], u[7]);
        }

        // ---- B tile -> LDS (swizzled): centersT[n][k0..k0+63] ----
        #pragma unroll
        for (int j = 0; j < 8; j++) {
            int g  = j * 256 + tid;          // 2048 16B chunks
            int n  = g >> 3;
            int kl = g & 7;
            Bs4[n * 8 + (kl ^ (n & 7))] = ctv[n * 128 + (k0 >> 3) + kl];
        }

        __syncthreads();

        // ---- MFMA: 2 k-steps of 32 ----
        #pragma unroll
        for (int ks = 0; ks < 2; ++ks) {
            const int lc = ks * 4 + quad;    // logical chunk within tile
            f16x8 af[4], bfr[4];
            #pragma unroll
            for (int mt = 0; mt < 4; mt++)
                af[mt] = ((const f16x8*)As4)[(mt * 16 + ml) * 8 + (lc ^ mls)];
            #pragma unroll
            for (int nt = 0; nt < 4; nt++) {
                const int col = w * 64 + nt * 16 + ml;
                bfr[nt] = ((const f16x8*)Bs4)[col * 8 + (lc ^ mls)];
            }
            #pragma unroll
            for (int mt = 0; mt < 4; mt++)
                #pragma unroll
                for (int nt = 0; nt < 4; nt++)
                    acc[mt][nt] = __builtin_amdgcn_mfma_f32_16x16x32_f16(
                        af[mt], bfr[nt], acc[mt][nt], 0, 0, 0);
        }
    }

    // ---- reductions: alias the A buffer (k-loop reads are done) ----
    __syncthreads();
    float* S = (float*)As4;   // [0..255] per-thread rc, [256..319] rowcnt, [320..323] wave partials
    S[tid] = (float)((rcp & 0xFFFFu) + (rcp >> 16));
    __syncthreads();
    if (tid < MT)
        S[256 + tid] = S[tid*4] + S[tid*4+1] + S[tid*4+2] + S[tid*4+3];
    __syncthreads();

    // ---- epilogue: fold features once; t2 folds in as a per-thread scalar ----
    float part = t2;
    #pragma unroll
    for (int mt = 0; mt < 4; mt++) {
        #pragma unroll
        for (int nt = 0; nt < 4; nt++) {
            const int n = w * 64 + nt * 16 + ml;
            #pragma unroll
            for (int reg = 0; reg < 4; reg++) {
                const int ri = mt * 16 + quad * 4 + reg;
                const float f = features[(size_t)(m0 + ri) * FEAT + n];
                const float T = acc[mt][nt][reg];
                part += f * (S[256 + ri] * f - 2.f * T);
            }
        }
    }
    #pragma unroll
    for (int off = 32; off > 0; off >>= 1) part += __shfl_down(part, off);
    if (lane == 0) S[320 + w] = part;
    __syncthreads();
    if (tid == 0)
        atomicAdd(out, (S[320] + S[321] + S[322] + S[323]) * (1.f / (float)N_ROWS));
}

extern "C" void kernel_launch(void* const* d_in, const int* in_sizes, int n_in,
                              void* d_out, int out_size, void* d_ws, size_t ws_size,
                              hipStream_t stream) {
    const int*   gt       = (const int*)d_in[0];
    const float* features = (const float*)d_in[1];
    const float* centers  = (const float*)d_in[2];
    float*       out      = (float*)d_out;

    ushort* centersT = (ushort*)d_ws;                                   // 512 KB
    ushort* csqh     = (ushort*)((char*)d_ws + (size_t)FEAT * KPAD * 2); // 2 KB

    prep_kernel<<<KPAD, 256, 0, stream>>>(centers, centersT, csqh, out);
    main_kernel<<<N_ROWS / MT, 256, 0, stream>>>(gt, features, centersT, csqh, out);
}